// Round 6
// baseline (429.170 us; speedup 1.0000x reference)
//
#include <hip/hip_runtime.h>
#include <math.h>

#define EPS 1e-8f

__device__ __forceinline__ float wave_reduce_sum(float v) {
#pragma unroll
  for (int off = 32; off > 0; off >>= 1)
    v += __shfl_xor(v, off, 64);
  return v;
}

__device__ __forceinline__ float wave_reduce_max(float v) {
#pragma unroll
  for (int off = 32; off > 0; off >>= 1)
    v = fmaxf(v, __shfl_xor(v, off, 64));
  return v;
}

__device__ __forceinline__ float sg16_reduce(float v) {
#pragma unroll
  for (int off = 1; off <= 8; off <<= 1) v += __shfl_xor(v, off);
  return v;
}

__device__ __forceinline__ float dot4(float4 a, float4 b) {
  return a.x * b.x + a.y * b.y + a.z * b.z + a.w * b.w;
}

// truncated-bf16 unpack: two fp32 from one uint holding two ushorts
__device__ __forceinline__ void unpack2(unsigned int w, float& a, float& b) {
  a = __uint_as_float(w << 16);
  b = __uint_as_float(w & 0xffff0000u);
}
__device__ __forceinline__ float4 unpack4_lo(uint4 w) {
  float4 r; unpack2(w.x, r.x, r.y); unpack2(w.y, r.z, r.w); return r;
}
__device__ __forceinline__ float4 unpack4_hi(uint4 w) {
  float4 r; unpack2(w.z, r.x, r.y); unpack2(w.w, r.z, r.w); return r;
}
__device__ __forceinline__ void recon2(unsigned int whi, unsigned int wlo,
                                       float& a, float& b) {
  a = __uint_as_float((whi << 16) | (wlo & 0xffffu));
  b = __uint_as_float((whi & 0xffff0000u) | (wlo >> 16));
}

// ---------------- counting sort by dst -> CSR ----------------
__global__ __launch_bounds__(256) void hist_kernel(const int* __restrict__ dst,
                                                   int* __restrict__ hist,
                                                   int E) {
  int e = blockIdx.x * blockDim.x + threadIdx.x;
  if (e < E) atomicAdd(&hist[dst[e]], 1);
}

__global__ __launch_bounds__(256) void scan_local(int* __restrict__ hist,
                                                  int* __restrict__ bsum,
                                                  int nb) {
  __shared__ int tsum[256];
  int t = threadIdx.x;
  int base = blockIdx.x * 1024 + t * 4;
  int v0 = 0, v1 = 0, v2 = 0, v3 = 0;
  if (base + 3 < nb) {
    int4 q = *(const int4*)&hist[base];
    v0 = q.x; v1 = q.y; v2 = q.z; v3 = q.w;
  } else {
    if (base + 0 < nb) v0 = hist[base + 0];
    if (base + 1 < nb) v1 = hist[base + 1];
    if (base + 2 < nb) v2 = hist[base + 2];
  }
  tsum[t] = v0 + v1 + v2 + v3;
  __syncthreads();
  for (int off = 1; off < 256; off <<= 1) {
    int u = 0;
    if (t >= off) u = tsum[t - off];
    __syncthreads();
    if (t >= off) tsum[t] += u;
    __syncthreads();
  }
  int excl = (t == 0) ? 0 : tsum[t - 1];
  int e0 = excl, e1 = excl + v0, e2 = e1 + v1, e3 = e2 + v2;
  if (base + 3 < nb) {
    *(int4*)&hist[base] = make_int4(e0, e1, e2, e3);
  } else {
    if (base + 0 < nb) hist[base + 0] = e0;
    if (base + 1 < nb) hist[base + 1] = e1;
    if (base + 2 < nb) hist[base + 2] = e2;
  }
  if (t == 255) bsum[blockIdx.x] = tsum[255];
}

__global__ __launch_bounds__(256) void scan_bsum(int* __restrict__ bsum,
                                                 int nblk) {
  __shared__ int sh[256];
  int t = threadIdx.x;
  sh[t] = (t < nblk) ? bsum[t] : 0;
  __syncthreads();
  for (int off = 1; off < 256; off <<= 1) {
    int u = 0;
    if (t >= off) u = sh[t - off];
    __syncthreads();
    if (t >= off) sh[t] += u;
    __syncthreads();
  }
  if (t < nblk) bsum[t] = (t == 0) ? 0 : sh[t - 1];
}

__global__ __launch_bounds__(256) void add_bsum(int* __restrict__ hist,
                                                const int* __restrict__ bsum,
                                                int nb) {
  int i = blockIdx.x * blockDim.x + threadIdx.x;
  if (i < nb) hist[i] += bsum[i >> 10];
}

__global__ __launch_bounds__(256) void scatter_kernel(
    const int* __restrict__ src, const int* __restrict__ dst,
    int* __restrict__ cursor, int* __restrict__ ssrc, int E) {
  int e = blockIdx.x * blockDim.x + threadIdx.x;
  if (e < E) {
    int pos = atomicAdd(&cursor[dst[e]], 1);
    ssrc[pos] = src[e];
  }
}

// ---------------- truncate fp32 -> hi16 plane -----------------
__global__ __launch_bounds__(256) void trunc16(const float* __restrict__ in,
                                               unsigned short* __restrict__ op,
                                               int n8) {
  int i = blockIdx.x * blockDim.x + threadIdx.x;
  if (i >= n8) return;
  const float4* p = (const float4*)(in + (size_t)i * 8);
  float4 a = p[0], b = p[1];
  uint4 w;
  w.x = (__float_as_uint(a.x) >> 16) | (__float_as_uint(a.y) & 0xffff0000u);
  w.y = (__float_as_uint(a.z) >> 16) | (__float_as_uint(a.w) & 0xffff0000u);
  w.z = (__float_as_uint(b.x) >> 16) | (__float_as_uint(b.y) & 0xffff0000u);
  w.w = (__float_as_uint(b.z) >> 16) | (__float_as_uint(b.w) & 0xffff0000u);
  *(uint4*)(op + (size_t)i * 8) = w;
}

// ---------------- node norms ----------------
template <int D>
__global__ __launch_bounds__(256) void node_norm(const float* __restrict__ x,
                                                 float* __restrict__ norms,
                                                 int N) {
  constexpr int V = D / 64;
  int node = (int)((blockIdx.x * blockDim.x + threadIdx.x) >> 6);
  int lane = threadIdx.x & 63;
  if (node >= N) return;
  const float* row = x + (size_t)node * D + lane * V;
  float ss = 0.f;
  if constexpr (V == 2) {
    float2 t = *(const float2*)row;
    ss = t.x * t.x + t.y * t.y;
  } else {
    float4 t = *(const float4*)row;
    ss = t.x * t.x + t.y * t.y + t.z * t.z + t.w * t.w;
  }
  ss = wave_reduce_sum(ss);
  if (lane == 0) norms[node] = sqrtf(ss);
}

__global__ __launch_bounds__(256) void node_norm_planes(
    const unsigned short* __restrict__ hi, const unsigned short* __restrict__ lo,
    float* __restrict__ norms, int N) {
  int node = (int)((blockIdx.x * blockDim.x + threadIdx.x) >> 6);
  int lane = threadIdx.x & 63;
  if (node >= N) return;
  size_t idx = (size_t)node * 256 + lane * 4;
  uint2 whi = *(const uint2*)(hi + idx);
  uint2 wlo = *(const uint2*)(lo + idx);
  float a, b, c, d;
  recon2(whi.x, wlo.x, a, b);
  recon2(whi.y, wlo.y, c, d);
  float ss = a * a + b * b + c * c + d * d;
  ss = wave_reduce_sum(ss);
  if (lane == 0) norms[node] = sqrtf(ss);
}

// ---------------- CSR conv with hi16 screen + exact recheck ----------------
template <int D, bool SPLIT>
__global__ __launch_bounds__(256) void csr_conv_scr(
    const float* __restrict__ xf,
    const unsigned short* __restrict__ hi,
    const unsigned short* __restrict__ lo,
    const float* __restrict__ norms,
    const int* __restrict__ ssrc, const int* __restrict__ endoff,
    float* __restrict__ agg, int N) {
  constexpr int CH = D / 64;
  constexpr int U = D / 128;
  int node = (int)((blockIdx.x * blockDim.x + threadIdx.x) >> 6);
  int lane = threadIdx.x & 63;
  if (node >= N) return;
  const int g = lane >> 4;
  const int l = lane & 15;
  int start = (node == 0) ? 0 : endoff[node - 1];
  int end = endoff[node];

  float4 dv[CH];
  if constexpr (SPLIT) {
#pragma unroll
    for (int u = 0; u < U; ++u) {
      size_t idx = (size_t)node * D + u * 128 + l * 8;
      uint4 whi = *(const uint4*)(hi + idx);
      uint4 wlo = *(const uint4*)(lo + idx);
      recon2(whi.x, wlo.x, dv[2 * u].x, dv[2 * u].y);
      recon2(whi.y, wlo.y, dv[2 * u].z, dv[2 * u].w);
      recon2(whi.z, wlo.z, dv[2 * u + 1].x, dv[2 * u + 1].y);
      recon2(whi.w, wlo.w, dv[2 * u + 1].z, dv[2 * u + 1].w);
    }
  } else {
#pragma unroll
    for (int u = 0; u < U; ++u) {
      const float* drow = xf + (size_t)node * D + u * 128 + l * 8;
      dv[2 * u] = *(const float4*)drow;
      dv[2 * u + 1] = *(const float4*)(drow + 4);
    }
  }
  float ssq = 0.f;
#pragma unroll
  for (int c = 0; c < CH; ++c) ssq += dot4(dv[c], dv[c]);
  ssq = sg16_reduce(ssq);
  float nd = sqrtf(ssq);

  float4 acc[CH];
#pragma unroll
  for (int c = 0; c < CH; ++c) acc[c] = make_float4(0.f, 0.f, 0.f, 0.f);

  uint4 wA[U], wB[U];
  float nsA = 1.f, nsB = 1.f;

  auto LOAD = [&](int e, uint4 (&w)[U], float& ns) {
    bool pe = e < end;
    int s = pe ? ssrc[e] : 0;
    ns = pe ? norms[s] : 1.0f;
#pragma unroll
    for (int u = 0; u < U; ++u)
      w[u] = pe ? *(const uint4*)(hi + (size_t)s * D + u * 128 + l * 8)
                : make_uint4(0, 0, 0, 0);
  };
  auto PROC = [&](int e, uint4 (&w)[U], float ns) {
    bool pe = e < end;
    float d = 0.f;
#pragma unroll
    for (int u = 0; u < U; ++u) {
      d += dot4(unpack4_lo(w[u]), dv[2 * u]);
      d += dot4(unpack4_hi(w[u]), dv[2 * u + 1]);
    }
    d = sg16_reduce(d);
    float denom = fmaxf(ns * nd, EPS);
    float thr = 0.5f * denom;
    float m = 0.011f * denom + 1e-7f;
    if (pe && d > thr - m) {
      int s = ssrc[e];
      float4 sv[CH];
      if constexpr (SPLIT) {
#pragma unroll
        for (int u = 0; u < U; ++u) {
          size_t idx = (size_t)s * D + u * 128 + l * 8;
          uint4 whi = *(const uint4*)(hi + idx);
          uint4 wlo = *(const uint4*)(lo + idx);
          recon2(whi.x, wlo.x, sv[2 * u].x, sv[2 * u].y);
          recon2(whi.y, wlo.y, sv[2 * u].z, sv[2 * u].w);
          recon2(whi.z, wlo.z, sv[2 * u + 1].x, sv[2 * u + 1].y);
          recon2(whi.w, wlo.w, sv[2 * u + 1].z, sv[2 * u + 1].w);
        }
      } else {
#pragma unroll
        for (int u = 0; u < U; ++u) {
          const float* r = xf + (size_t)s * D + u * 128 + l * 8;
          sv[2 * u] = *(const float4*)r;
          sv[2 * u + 1] = *(const float4*)(r + 4);
        }
      }
      float dx = 0.f;
#pragma unroll
      for (int c = 0; c < CH; ++c) dx += dot4(sv[c], dv[c]);
      dx = sg16_reduce(dx);
      if (dx > thr) {
#pragma unroll
        for (int c = 0; c < CH; ++c) {
          acc[c].x += sv[c].x; acc[c].y += sv[c].y;
          acc[c].z += sv[c].z; acc[c].w += sv[c].w;
        }
      }
    }
  };

  int eA = start + g;
  int eB = eA + 4;
  LOAD(eA, wA, nsA);
  for (int eb = start; eb < end; eb += 8) {
    LOAD(eB, wB, nsB);
    PROC(eA, wA, nsA);
    eA += 8;
    LOAD(eA, wA, nsA);
    PROC(eB, wB, nsB);
    eB += 8;
  }

#pragma unroll
  for (int c = 0; c < CH; ++c) {
    acc[c].x += __shfl_xor(acc[c].x, 16); acc[c].x += __shfl_xor(acc[c].x, 32);
    acc[c].y += __shfl_xor(acc[c].y, 16); acc[c].y += __shfl_xor(acc[c].y, 32);
    acc[c].z += __shfl_xor(acc[c].z, 16); acc[c].z += __shfl_xor(acc[c].z, 32);
    acc[c].w += __shfl_xor(acc[c].w, 16); acc[c].w += __shfl_xor(acc[c].w, 32);
  }
  bool selfpass = ssq > 0.5f * fmaxf(ssq, EPS);
  if (g == 0) {
#pragma unroll
    for (int u = 0; u < U; ++u) {
      float* arow = agg + (size_t)node * D + u * 128 + l * 8;
      float4 o0 = acc[2 * u], o1 = acc[2 * u + 1];
      if (selfpass) {
        o0.x += dv[2 * u].x; o0.y += dv[2 * u].y;
        o0.z += dv[2 * u].z; o0.w += dv[2 * u].w;
        o1.x += dv[2 * u + 1].x; o1.y += dv[2 * u + 1].y;
        o1.z += dv[2 * u + 1].z; o1.w += dv[2 * u + 1].w;
      }
      *(float4*)arow = o0;
      *(float4*)(arow + 4) = o1;
    }
  }
}

// ---------------- GEMM v2: C = act(A @ W^T + b) ----------------
// BMxBN block tile, TMx8 per-thread tile; per k-step each thread does TM*8
// FMAs on TM/4+2 float4 LDS reads -> compute-bound on the fp32 vector pipe.
// B columns split into two float4 groups (ns, ns+BN/2): lane LDS addresses
// stride 16B -> <=2-way bank aliasing (free).
template <int BM, int BN, int BK, int TM, bool RELU, bool TOSPLIT>
__global__ __launch_bounds__(256) void gemm_v2(
    const float* __restrict__ A, const float* __restrict__ W,
    const float* __restrict__ bias, float* __restrict__ C,
    unsigned short* __restrict__ hiP, unsigned short* __restrict__ loP,
    int M, int N, int K) {
  constexpr int NTX = BN / 8;       // threads along n (each owns 2x float4)
  constexpr int NTY = 256 / NTX;    // threads along m
  static_assert(BM == NTY * TM, "tile shape");
  constexpr int KQ = BK / 4;
  constexpr int L4A = BM * KQ / 256;
  constexpr int L4B = BN * KQ / 256;
  __shared__ float As[BK][BM];
  __shared__ float Bs[BK][BN];
  const int tid = threadIdx.x;
  const int m0 = blockIdx.x * BM;
  const int n0 = blockIdx.y * BN;
  const int tx = tid % NTX;
  const int ty = tid / NTX;
  const int ms = ty * TM;
  const int ns = tx * 4;           // group0 cols; group1 at ns + BN/2
  float acc[TM][8] = {};
  for (int k0 = 0; k0 < K; k0 += BK) {
#pragma unroll
    for (int t = 0; t < L4A; ++t) {
      int f = tid + t * 256;
      int row = f / KQ, kq = f % KQ;
      int gm = m0 + row;
      float4 a = (gm < M) ? *(const float4*)&A[(size_t)gm * K + k0 + kq * 4]
                          : make_float4(0.f, 0.f, 0.f, 0.f);
      As[kq * 4 + 0][row] = a.x; As[kq * 4 + 1][row] = a.y;
      As[kq * 4 + 2][row] = a.z; As[kq * 4 + 3][row] = a.w;
    }
#pragma unroll
    for (int t = 0; t < L4B; ++t) {
      int f = tid + t * 256;
      int row = f / KQ, kq = f % KQ;
      float4 b = *(const float4*)&W[(size_t)(n0 + row) * K + k0 + kq * 4];
      Bs[kq * 4 + 0][row] = b.x; Bs[kq * 4 + 1][row] = b.y;
      Bs[kq * 4 + 2][row] = b.z; Bs[kq * 4 + 3][row] = b.w;
    }
    __syncthreads();
#pragma unroll
    for (int kk = 0; kk < BK; ++kk) {
      float av[TM];
#pragma unroll
      for (int i = 0; i < TM / 4; ++i) {
        float4 t = *(const float4*)&As[kk][ms + i * 4];
        av[i * 4 + 0] = t.x; av[i * 4 + 1] = t.y;
        av[i * 4 + 2] = t.z; av[i * 4 + 3] = t.w;
      }
      float4 b0 = *(const float4*)&Bs[kk][ns];
      float4 b1 = *(const float4*)&Bs[kk][ns + BN / 2];
      float bv[8] = {b0.x, b0.y, b0.z, b0.w, b1.x, b1.y, b1.z, b1.w};
#pragma unroll
      for (int i = 0; i < TM; ++i)
#pragma unroll
        for (int j = 0; j < 8; ++j) acc[i][j] += av[i] * bv[j];
    }
    __syncthreads();
  }
  float4 bb0 = *(const float4*)&bias[n0 + ns];
  float4 bb1 = *(const float4*)&bias[n0 + BN / 2 + ns];
  float bv[8] = {bb0.x, bb0.y, bb0.z, bb0.w, bb1.x, bb1.y, bb1.z, bb1.w};
#pragma unroll
  for (int i = 0; i < TM; ++i) {
    int gm = m0 + ms + i;
    if (gm >= M) continue;
    float t[8];
#pragma unroll
    for (int j = 0; j < 8; ++j) {
      t[j] = acc[i][j] + bv[j];
      if (RELU) t[j] = fmaxf(t[j], 0.f);
    }
#pragma unroll
    for (int grp = 0; grp < 2; ++grp) {
      size_t idx = (size_t)gm * N + n0 + grp * (BN / 2) + ns;
      float* tg = t + grp * 4;
      if (TOSPLIT) {
        unsigned int c0 = __float_as_uint(tg[0]), c1 = __float_as_uint(tg[1]);
        unsigned int c2 = __float_as_uint(tg[2]), c3 = __float_as_uint(tg[3]);
        uint2 whi = {(c0 >> 16) | (c1 & 0xffff0000u),
                     (c2 >> 16) | (c3 & 0xffff0000u)};
        uint2 wlo = {(c0 & 0xffffu) | (c1 << 16),
                     (c2 & 0xffffu) | (c3 << 16)};
        *(uint2*)(hiP + idx) = whi;
        *(uint2*)(loP + idx) = wlo;
      } else {
        float4 o = {tg[0], tg[1], tg[2], tg[3]};
        *(float4*)&C[idx] = o;
      }
    }
  }
}

__global__ __launch_bounds__(256) void log_softmax64(float* __restrict__ out,
                                                     int N) {
  int row = (int)((blockIdx.x * blockDim.x + threadIdx.x) >> 6);
  int lane = threadIdx.x & 63;
  if (row >= N) return;
  float v = out[(size_t)row * 64 + lane];
  float mx = wave_reduce_max(v);
  float e = expf(v - mx);
  float s = wave_reduce_sum(e);
  out[(size_t)row * 64 + lane] = v - mx - logf(s);
}

extern "C" void kernel_launch(void* const* d_in, const int* in_sizes, int n_in,
                              void* d_out, int out_size, void* d_ws,
                              size_t ws_size, hipStream_t stream) {
  const float* x  = (const float*)d_in[0];
  const int* eidx = (const int*)d_in[1];
  const float* W1 = (const float*)d_in[2];
  const float* b1 = (const float*)d_in[3];
  const float* W2 = (const float*)d_in[4];
  const float* b2 = (const float*)d_in[5];
  float* out = (float*)d_out;

  const int N = in_sizes[0] / 128;  // 50000
  const int E = in_sizes[1] / 2;    // 800000
  const int* src = eidx;
  const int* dst = eidx + E;

  float* agg   = (float*)d_ws;
  float* norms = agg + (size_t)N * 256;
  float* normh = norms + N;
  int* cursor  = (int*)(normh + N);
  int* ssrc    = cursor + N;
  int* bsum    = ssrc + E;
  unsigned short* hiP = (unsigned short*)(bsum + 256);
  unsigned short* loP = hiP + (size_t)N * 256;
  unsigned short* xbf = hiP;  // overlap (dead before GEMM1 writes hiP)

  const int nblk = (N + 1023) / 1024;

  // ---- build CSR (by dst), shared by both layers ----
  hipMemsetAsync(cursor, 0, (size_t)N * sizeof(int), stream);
  hist_kernel<<<(E + 255) / 256, 256, 0, stream>>>(dst, cursor, E);
  scan_local<<<nblk, 256, 0, stream>>>(cursor, bsum, N);
  scan_bsum<<<1, 256, 0, stream>>>(bsum, nblk);
  add_bsum<<<(N + 255) / 256, 256, 0, stream>>>(cursor, bsum, N);
  scatter_kernel<<<(E + 255) / 256, 256, 0, stream>>>(src, dst, cursor, ssrc, E);

  // ---- layer 1 (D=128) ----
  trunc16<<<((N * 128 / 8) + 255) / 256, 256, 0, stream>>>(x, xbf, N * 128 / 8);
  node_norm<128><<<(N + 3) / 4, 256, 0, stream>>>(x, norms, N);
  csr_conv_scr<128, false><<<(N + 3) / 4, 256, 0, stream>>>(
      x, xbf, nullptr, norms, ssrc, cursor, agg, N);
  gemm_v2<128, 128, 32, 8, true, true>
      <<<dim3((N + 127) / 128, 2), 256, 0, stream>>>(
          agg, W1, b1, nullptr, hiP, loP, N, 256, 128);

  // ---- layer 2 (D=256) ----
  node_norm_planes<<<(N + 3) / 4, 256, 0, stream>>>(hiP, loP, normh, N);
  csr_conv_scr<256, true><<<(N + 3) / 4, 256, 0, stream>>>(
      nullptr, hiP, loP, normh, ssrc, cursor, agg, N);
  gemm_v2<128, 64, 32, 4, false, false>
      <<<dim3((N + 127) / 128, 1), 256, 0, stream>>>(
          agg, W2, b2, out, nullptr, nullptr, N, 64, 256);

  log_softmax64<<<(N + 3) / 4, 256, 0, stream>>>(out, N);
}

// Round 7
// 369.205 us; speedup vs baseline: 1.1624x; 1.1624x over previous
//
#include <hip/hip_runtime.h>
#include <math.h>

#define EPS 1e-8f
#define NB_SORT 256  // blocks in coarse sort phases

__device__ __forceinline__ float wave_reduce_sum(float v) {
#pragma unroll
  for (int off = 32; off > 0; off >>= 1)
    v += __shfl_xor(v, off, 64);
  return v;
}

__device__ __forceinline__ float wave_reduce_max(float v) {
#pragma unroll
  for (int off = 32; off > 0; off >>= 1)
    v = fmaxf(v, __shfl_xor(v, off, 64));
  return v;
}

__device__ __forceinline__ float sg16_reduce(float v) {
#pragma unroll
  for (int off = 1; off <= 8; off <<= 1) v += __shfl_xor(v, off);
  return v;
}

__device__ __forceinline__ float dot4(float4 a, float4 b) {
  return a.x * b.x + a.y * b.y + a.z * b.z + a.w * b.w;
}

__device__ __forceinline__ void unpack2(unsigned int w, float& a, float& b) {
  a = __uint_as_float(w << 16);
  b = __uint_as_float(w & 0xffff0000u);
}
__device__ __forceinline__ float4 unpack4_lo(uint4 w) {
  float4 r; unpack2(w.x, r.x, r.y); unpack2(w.y, r.z, r.w); return r;
}
__device__ __forceinline__ float4 unpack4_hi(uint4 w) {
  float4 r; unpack2(w.z, r.x, r.y); unpack2(w.w, r.z, r.w); return r;
}
__device__ __forceinline__ void recon2(unsigned int whi, unsigned int wlo,
                                       float& a, float& b) {
  a = __uint_as_float((whi << 16) | (wlo & 0xffffu));
  b = __uint_as_float((whi & 0xffff0000u) | (wlo >> 16));
}

// ============ CSR build: 2-level bucket sort, LDS atomics only ============
// Coarse bucket = dst >> 6 (64 dst values per bucket).

// Phase A: per-block LDS histogram over coarse buckets -> hist_blk[bucket][blk]
__global__ __launch_bounds__(256) void hist_coarse(const int* __restrict__ dst,
                                                   int* __restrict__ hist_blk,
                                                   int E, int nbuck) {
  __shared__ int lh[1024];
  int t = threadIdx.x, blk = blockIdx.x;
  for (int i = t; i < nbuck; i += 256) lh[i] = 0;
  __syncthreads();
  int ch = (E + NB_SORT - 1) / NB_SORT;
  int lo = blk * ch, hi = min(E, lo + ch);
  for (int e = lo + t; e < hi; e += 256) atomicAdd(&lh[dst[e] >> 6], 1);
  __syncthreads();
  for (int i = t; i < nbuck; i += 256) hist_blk[i * NB_SORT + blk] = lh[i];
}

// Hierarchical exclusive scan (1024 elems/block, 4/thread)
__global__ __launch_bounds__(256) void scan_local(int* __restrict__ hist,
                                                  int* __restrict__ bsum,
                                                  int nb) {
  __shared__ int tsum[256];
  int t = threadIdx.x;
  int base = blockIdx.x * 1024 + t * 4;
  int v0 = 0, v1 = 0, v2 = 0, v3 = 0;
  if (base + 3 < nb) {
    int4 q = *(const int4*)&hist[base];
    v0 = q.x; v1 = q.y; v2 = q.z; v3 = q.w;
  } else {
    if (base + 0 < nb) v0 = hist[base + 0];
    if (base + 1 < nb) v1 = hist[base + 1];
    if (base + 2 < nb) v2 = hist[base + 2];
  }
  tsum[t] = v0 + v1 + v2 + v3;
  __syncthreads();
  for (int off = 1; off < 256; off <<= 1) {
    int u = 0;
    if (t >= off) u = tsum[t - off];
    __syncthreads();
    if (t >= off) tsum[t] += u;
    __syncthreads();
  }
  int excl = (t == 0) ? 0 : tsum[t - 1];
  int e0 = excl, e1 = excl + v0, e2 = e1 + v1, e3 = e2 + v2;
  if (base + 3 < nb) {
    *(int4*)&hist[base] = make_int4(e0, e1, e2, e3);
  } else {
    if (base + 0 < nb) hist[base + 0] = e0;
    if (base + 1 < nb) hist[base + 1] = e1;
    if (base + 2 < nb) hist[base + 2] = e2;
  }
  if (t == 255) bsum[blockIdx.x] = tsum[255];
}

__global__ __launch_bounds__(256) void scan_bsum(int* __restrict__ bsum,
                                                 int nblk) {
  __shared__ int sh[256];
  int t = threadIdx.x;
  sh[t] = (t < nblk) ? bsum[t] : 0;
  __syncthreads();
  for (int off = 1; off < 256; off <<= 1) {
    int u = 0;
    if (t >= off) u = sh[t - off];
    __syncthreads();
    if (t >= off) sh[t] += u;
    __syncthreads();
  }
  if (t < nblk) bsum[t] = (t == 0) ? 0 : sh[t - 1];
}

__global__ __launch_bounds__(256) void add_bsum(int* __restrict__ hist,
                                                const int* __restrict__ bsum,
                                                int nb) {
  int i = blockIdx.x * blockDim.x + threadIdx.x;
  if (i < nb) hist[i] += bsum[i >> 10];
}

// Phase B: coarse scatter with LDS cursors seeded from scan
__global__ __launch_bounds__(256) void scatter_coarse(
    const int* __restrict__ src, const int* __restrict__ dst,
    const int* __restrict__ S, int2* __restrict__ epair, int E, int nbuck) {
  __shared__ int lb[1024];
  int t = threadIdx.x, blk = blockIdx.x;
  for (int i = t; i < nbuck; i += 256) lb[i] = S[i * NB_SORT + blk];
  __syncthreads();
  int ch = (E + NB_SORT - 1) / NB_SORT;
  int lo = blk * ch, hi = min(E, lo + ch);
  for (int e = lo + t; e < hi; e += 256) {
    int d = dst[e];
    int pos = atomicAdd(&lb[d >> 6], 1);
    epair[pos] = make_int2(src[e], d);
  }
}

// Phase C: one block per bucket; 64-bin LDS counting sort -> ssrc + endoff
__global__ __launch_bounds__(256) void fine_sort(
    const int2* __restrict__ epair, const int* __restrict__ S,
    int* __restrict__ ssrc, int* __restrict__ endoff, int E, int nbuck,
    int N) {
  __shared__ int fh[64];
  __shared__ int cur[64];
  int b = blockIdx.x, t = threadIdx.x;
  int bstart = S[b * NB_SORT];
  int bend = (b + 1 < nbuck) ? S[(b + 1) * NB_SORT] : E;
  if (t < 64) fh[t] = 0;
  __syncthreads();
  for (int e = bstart + t; e < bend; e += 256)
    atomicAdd(&fh[epair[e].y & 63], 1);
  __syncthreads();
  if (t < 64) {  // wave 0: inclusive scan of 64 bins
    int v = fh[t];
    int incl = v;
#pragma unroll
    for (int off = 1; off < 64; off <<= 1) {
      int u = __shfl_up(incl, off, 64);
      if (t >= off) incl += u;
    }
    cur[t] = incl - v;  // exclusive prefix = local write cursor
    int d = b * 64 + t;
    if (d < N) endoff[d] = bstart + incl;
  }
  __syncthreads();
  for (int e = bstart + t; e < bend; e += 256) {
    int2 p = epair[e];
    int pos = atomicAdd(&cur[p.y & 63], 1);
    ssrc[bstart + pos] = p.x;
  }
}

// ============ layer-1 prep: fused truncate + norm (one pass over x) =======
__global__ __launch_bounds__(256) void prep_x(const float* __restrict__ x,
                                              unsigned short* __restrict__ xbf,
                                              float* __restrict__ norms,
                                              int N) {
  int node = (int)((blockIdx.x * blockDim.x + threadIdx.x) >> 6);
  int lane = threadIdx.x & 63;
  if (node >= N) return;
  float2 v = *(const float2*)(x + (size_t)node * 128 + lane * 2);
  unsigned int w =
      (__float_as_uint(v.x) >> 16) | (__float_as_uint(v.y) & 0xffff0000u);
  ((unsigned int*)(xbf + (size_t)node * 128))[lane] = w;
  float ss = wave_reduce_sum(v.x * v.x + v.y * v.y);
  if (lane == 0) norms[node] = sqrtf(ss);
}

__global__ __launch_bounds__(256) void node_norm_planes(
    const unsigned short* __restrict__ hi, const unsigned short* __restrict__ lo,
    float* __restrict__ norms, int N) {
  int node = (int)((blockIdx.x * blockDim.x + threadIdx.x) >> 6);
  int lane = threadIdx.x & 63;
  if (node >= N) return;
  size_t idx = (size_t)node * 256 + lane * 4;
  uint2 whi = *(const uint2*)(hi + idx);
  uint2 wlo = *(const uint2*)(lo + idx);
  float a, b, c, d;
  recon2(whi.x, wlo.x, a, b);
  recon2(whi.y, wlo.y, c, d);
  float ss = a * a + b * b + c * c + d * d;
  ss = wave_reduce_sum(ss);
  if (lane == 0) norms[node] = sqrtf(ss);
}

// ---------------- CSR conv with hi16 screen + exact recheck ----------------
template <int D, bool SPLIT>
__global__ __launch_bounds__(256) void csr_conv_scr(
    const float* __restrict__ xf,
    const unsigned short* __restrict__ hi,
    const unsigned short* __restrict__ lo,
    const float* __restrict__ norms,
    const int* __restrict__ ssrc, const int* __restrict__ endoff,
    float* __restrict__ agg, int N) {
  constexpr int CH = D / 64;
  constexpr int U = D / 128;
  int node = (int)((blockIdx.x * blockDim.x + threadIdx.x) >> 6);
  int lane = threadIdx.x & 63;
  if (node >= N) return;
  const int g = lane >> 4;
  const int l = lane & 15;
  int start = (node == 0) ? 0 : endoff[node - 1];
  int end = endoff[node];

  float4 dv[CH];
  if constexpr (SPLIT) {
#pragma unroll
    for (int u = 0; u < U; ++u) {
      size_t idx = (size_t)node * D + u * 128 + l * 8;
      uint4 whi = *(const uint4*)(hi + idx);
      uint4 wlo = *(const uint4*)(lo + idx);
      recon2(whi.x, wlo.x, dv[2 * u].x, dv[2 * u].y);
      recon2(whi.y, wlo.y, dv[2 * u].z, dv[2 * u].w);
      recon2(whi.z, wlo.z, dv[2 * u + 1].x, dv[2 * u + 1].y);
      recon2(whi.w, wlo.w, dv[2 * u + 1].z, dv[2 * u + 1].w);
    }
  } else {
#pragma unroll
    for (int u = 0; u < U; ++u) {
      const float* drow = xf + (size_t)node * D + u * 128 + l * 8;
      dv[2 * u] = *(const float4*)drow;
      dv[2 * u + 1] = *(const float4*)(drow + 4);
    }
  }
  float ssq = 0.f;
#pragma unroll
  for (int c = 0; c < CH; ++c) ssq += dot4(dv[c], dv[c]);
  ssq = sg16_reduce(ssq);
  float nd = sqrtf(ssq);

  float4 acc[CH];
#pragma unroll
  for (int c = 0; c < CH; ++c) acc[c] = make_float4(0.f, 0.f, 0.f, 0.f);

  uint4 wA[U], wB[U];
  float nsA = 1.f, nsB = 1.f;

  auto LOAD = [&](int e, uint4 (&w)[U], float& ns) {
    bool pe = e < end;
    int s = pe ? ssrc[e] : 0;
    ns = pe ? norms[s] : 1.0f;
#pragma unroll
    for (int u = 0; u < U; ++u)
      w[u] = pe ? *(const uint4*)(hi + (size_t)s * D + u * 128 + l * 8)
                : make_uint4(0, 0, 0, 0);
  };
  auto PROC = [&](int e, uint4 (&w)[U], float ns) {
    bool pe = e < end;
    float d = 0.f;
#pragma unroll
    for (int u = 0; u < U; ++u) {
      d += dot4(unpack4_lo(w[u]), dv[2 * u]);
      d += dot4(unpack4_hi(w[u]), dv[2 * u + 1]);
    }
    d = sg16_reduce(d);
    float denom = fmaxf(ns * nd, EPS);
    float thr = 0.5f * denom;
    float m = 0.011f * denom + 1e-7f;
    if (pe && d > thr - m) {
      int s = ssrc[e];
      float4 sv[CH];
      if constexpr (SPLIT) {
#pragma unroll
        for (int u = 0; u < U; ++u) {
          size_t idx = (size_t)s * D + u * 128 + l * 8;
          uint4 whi = *(const uint4*)(hi + idx);
          uint4 wlo = *(const uint4*)(lo + idx);
          recon2(whi.x, wlo.x, sv[2 * u].x, sv[2 * u].y);
          recon2(whi.y, wlo.y, sv[2 * u].z, sv[2 * u].w);
          recon2(whi.z, wlo.z, sv[2 * u + 1].x, sv[2 * u + 1].y);
          recon2(whi.w, wlo.w, sv[2 * u + 1].z, sv[2 * u + 1].w);
        }
      } else {
#pragma unroll
        for (int u = 0; u < U; ++u) {
          const float* r = xf + (size_t)s * D + u * 128 + l * 8;
          sv[2 * u] = *(const float4*)r;
          sv[2 * u + 1] = *(const float4*)(r + 4);
        }
      }
      float dx = 0.f;
#pragma unroll
      for (int c = 0; c < CH; ++c) dx += dot4(sv[c], dv[c]);
      dx = sg16_reduce(dx);
      if (dx > thr) {
#pragma unroll
        for (int c = 0; c < CH; ++c) {
          acc[c].x += sv[c].x; acc[c].y += sv[c].y;
          acc[c].z += sv[c].z; acc[c].w += sv[c].w;
        }
      }
    }
  };

  int eA = start + g;
  int eB = eA + 4;
  LOAD(eA, wA, nsA);
  for (int eb = start; eb < end; eb += 8) {
    LOAD(eB, wB, nsB);
    PROC(eA, wA, nsA);
    eA += 8;
    LOAD(eA, wA, nsA);
    PROC(eB, wB, nsB);
    eB += 8;
  }

#pragma unroll
  for (int c = 0; c < CH; ++c) {
    acc[c].x += __shfl_xor(acc[c].x, 16); acc[c].x += __shfl_xor(acc[c].x, 32);
    acc[c].y += __shfl_xor(acc[c].y, 16); acc[c].y += __shfl_xor(acc[c].y, 32);
    acc[c].z += __shfl_xor(acc[c].z, 16); acc[c].z += __shfl_xor(acc[c].z, 32);
    acc[c].w += __shfl_xor(acc[c].w, 16); acc[c].w += __shfl_xor(acc[c].w, 32);
  }
  bool selfpass = ssq > 0.5f * fmaxf(ssq, EPS);
  if (g == 0) {
#pragma unroll
    for (int u = 0; u < U; ++u) {
      float* arow = agg + (size_t)node * D + u * 128 + l * 8;
      float4 o0 = acc[2 * u], o1 = acc[2 * u + 1];
      if (selfpass) {
        o0.x += dv[2 * u].x; o0.y += dv[2 * u].y;
        o0.z += dv[2 * u].z; o0.w += dv[2 * u].w;
        o1.x += dv[2 * u + 1].x; o1.y += dv[2 * u + 1].y;
        o1.z += dv[2 * u + 1].z; o1.w += dv[2 * u + 1].w;
      }
      *(float4*)arow = o0;
      *(float4*)(arow + 4) = o1;
    }
  }
}

// ---------------- GEMM v2: C = act(A @ W^T + b) ----------------
template <int BM, int BN, int BK, int TM, bool RELU, bool TOSPLIT>
__global__ __launch_bounds__(256) void gemm_v2(
    const float* __restrict__ A, const float* __restrict__ W,
    const float* __restrict__ bias, float* __restrict__ C,
    unsigned short* __restrict__ hiP, unsigned short* __restrict__ loP,
    int M, int N, int K) {
  constexpr int NTX = BN / 8;
  constexpr int NTY = 256 / NTX;
  static_assert(BM == NTY * TM, "tile shape");
  constexpr int KQ = BK / 4;
  constexpr int L4A = BM * KQ / 256;
  constexpr int L4B = BN * KQ / 256;
  __shared__ float As[BK][BM];
  __shared__ float Bs[BK][BN];
  const int tid = threadIdx.x;
  const int m0 = blockIdx.x * BM;
  const int n0 = blockIdx.y * BN;
  const int tx = tid % NTX;
  const int ty = tid / NTX;
  const int ms = ty * TM;
  const int ns = tx * 4;
  float acc[TM][8] = {};
  for (int k0 = 0; k0 < K; k0 += BK) {
#pragma unroll
    for (int t = 0; t < L4A; ++t) {
      int f = tid + t * 256;
      int row = f / KQ, kq = f % KQ;
      int gm = m0 + row;
      float4 a = (gm < M) ? *(const float4*)&A[(size_t)gm * K + k0 + kq * 4]
                          : make_float4(0.f, 0.f, 0.f, 0.f);
      As[kq * 4 + 0][row] = a.x; As[kq * 4 + 1][row] = a.y;
      As[kq * 4 + 2][row] = a.z; As[kq * 4 + 3][row] = a.w;
    }
#pragma unroll
    for (int t = 0; t < L4B; ++t) {
      int f = tid + t * 256;
      int row = f / KQ, kq = f % KQ;
      float4 b = *(const float4*)&W[(size_t)(n0 + row) * K + k0 + kq * 4];
      Bs[kq * 4 + 0][row] = b.x; Bs[kq * 4 + 1][row] = b.y;
      Bs[kq * 4 + 2][row] = b.z; Bs[kq * 4 + 3][row] = b.w;
    }
    __syncthreads();
#pragma unroll
    for (int kk = 0; kk < BK; ++kk) {
      float av[TM];
#pragma unroll
      for (int i = 0; i < TM / 4; ++i) {
        float4 t = *(const float4*)&As[kk][ms + i * 4];
        av[i * 4 + 0] = t.x; av[i * 4 + 1] = t.y;
        av[i * 4 + 2] = t.z; av[i * 4 + 3] = t.w;
      }
      float4 b0 = *(const float4*)&Bs[kk][ns];
      float4 b1 = *(const float4*)&Bs[kk][ns + BN / 2];
      float bv[8] = {b0.x, b0.y, b0.z, b0.w, b1.x, b1.y, b1.z, b1.w};
#pragma unroll
      for (int i = 0; i < TM; ++i)
#pragma unroll
        for (int j = 0; j < 8; ++j) acc[i][j] += av[i] * bv[j];
    }
    __syncthreads();
  }
  float4 bb0 = *(const float4*)&bias[n0 + ns];
  float4 bb1 = *(const float4*)&bias[n0 + BN / 2 + ns];
  float bv[8] = {bb0.x, bb0.y, bb0.z, bb0.w, bb1.x, bb1.y, bb1.z, bb1.w};
#pragma unroll
  for (int i = 0; i < TM; ++i) {
    int gm = m0 + ms + i;
    if (gm >= M) continue;
    float t[8];
#pragma unroll
    for (int j = 0; j < 8; ++j) {
      t[j] = acc[i][j] + bv[j];
      if (RELU) t[j] = fmaxf(t[j], 0.f);
    }
#pragma unroll
    for (int grp = 0; grp < 2; ++grp) {
      size_t idx = (size_t)gm * N + n0 + grp * (BN / 2) + ns;
      float* tg = t + grp * 4;
      if (TOSPLIT) {
        unsigned int c0 = __float_as_uint(tg[0]), c1 = __float_as_uint(tg[1]);
        unsigned int c2 = __float_as_uint(tg[2]), c3 = __float_as_uint(tg[3]);
        uint2 whi = {(c0 >> 16) | (c1 & 0xffff0000u),
                     (c2 >> 16) | (c3 & 0xffff0000u)};
        uint2 wlo = {(c0 & 0xffffu) | (c1 << 16),
                     (c2 & 0xffffu) | (c3 << 16)};
        *(uint2*)(hiP + idx) = whi;
        *(uint2*)(loP + idx) = wlo;
      } else {
        float4 o = {tg[0], tg[1], tg[2], tg[3]};
        *(float4*)&C[idx] = o;
      }
    }
  }
}

__global__ __launch_bounds__(256) void log_softmax64(float* __restrict__ out,
                                                     int N) {
  int row = (int)((blockIdx.x * blockDim.x + threadIdx.x) >> 6);
  int lane = threadIdx.x & 63;
  if (row >= N) return;
  float v = out[(size_t)row * 64 + lane];
  float mx = wave_reduce_max(v);
  float e = expf(v - mx);
  float s = wave_reduce_sum(e);
  out[(size_t)row * 64 + lane] = v - mx - logf(s);
}

extern "C" void kernel_launch(void* const* d_in, const int* in_sizes, int n_in,
                              void* d_out, int out_size, void* d_ws,
                              size_t ws_size, hipStream_t stream) {
  const float* x  = (const float*)d_in[0];
  const int* eidx = (const int*)d_in[1];
  const float* W1 = (const float*)d_in[2];
  const float* b1 = (const float*)d_in[3];
  const float* W2 = (const float*)d_in[4];
  const float* b2 = (const float*)d_in[5];
  float* out = (float*)d_out;

  const int N = in_sizes[0] / 128;  // 50000
  const int E = in_sizes[1] / 2;    // 800000
  const int* src = eidx;
  const int* dst = eidx + E;

  const int nbuck = (N + 63) / 64;        // 782 coarse buckets
  const int ntot = nbuck * NB_SORT;       // scan length (200192)
  const int nblk2 = (ntot + 1023) / 1024; // 196

  // ws layout: agg[N*256] f | norms[N] f | normh[N] f | S[ntot] i |
  //            bsum[256] i | ssrc[E] i | endoff[N] i | hi[N*256] u16 |
  //            lo[N*256] u16.  epair (E int2) overlaps lo; xbf (N*128 u16)
  //            overlaps hi — both dead before GEMM1 writes the planes.
  float* agg    = (float*)d_ws;
  float* norms  = agg + (size_t)N * 256;
  float* normh  = norms + N;
  int* S        = (int*)(normh + N);
  int* bsum     = S + ntot;
  int* ssrc     = bsum + 256;
  int* endoff   = ssrc + E;
  unsigned short* hiP = (unsigned short*)(endoff + N);
  unsigned short* loP = hiP + (size_t)N * 256;
  unsigned short* xbf = hiP;          // overlap
  int2* epair   = (int2*)loP;         // overlap

  // ---- build CSR (by dst) with LDS-only atomics ----
  hist_coarse<<<NB_SORT, 256, 0, stream>>>(dst, S, E, nbuck);
  scan_local<<<nblk2, 256, 0, stream>>>(S, bsum, ntot);
  scan_bsum<<<1, 256, 0, stream>>>(bsum, nblk2);
  add_bsum<<<(ntot + 255) / 256, 256, 0, stream>>>(S, bsum, ntot);
  scatter_coarse<<<NB_SORT, 256, 0, stream>>>(src, dst, S, epair, E, nbuck);
  fine_sort<<<nbuck, 256, 0, stream>>>(epair, S, ssrc, endoff, E, nbuck, N);

  // ---- layer 1 (D=128) ----
  prep_x<<<(N + 3) / 4, 256, 0, stream>>>(x, xbf, norms, N);
  csr_conv_scr<128, false><<<(N + 3) / 4, 256, 0, stream>>>(
      x, xbf, nullptr, norms, ssrc, endoff, agg, N);
  gemm_v2<128, 128, 32, 8, true, true>
      <<<dim3((N + 127) / 128, 2), 256, 0, stream>>>(
          agg, W1, b1, nullptr, hiP, loP, N, 256, 128);

  // ---- layer 2 (D=256) ----
  node_norm_planes<<<(N + 3) / 4, 256, 0, stream>>>(hiP, loP, normh, N);
  csr_conv_scr<256, true><<<(N + 3) / 4, 256, 0, stream>>>(
      nullptr, hiP, loP, normh, ssrc, endoff, agg, N);
  gemm_v2<128, 64, 32, 4, false, false>
      <<<dim3((N + 127) / 128, 1), 256, 0, stream>>>(
          agg, W2, b2, out, nullptr, nullptr, N, 64, 256);

  log_softmax64<<<(N + 3) / 4, 256, 0, stream>>>(out, N);
}